// Round 7
// baseline (260.246 us; speedup 1.0000x reference)
//
#include <hip/hip_runtime.h>

typedef __attribute__((ext_vector_type(8))) short bf16x8;
typedef __attribute__((ext_vector_type(4))) float f32x4;

__device__ __forceinline__ float bf2f(unsigned short u) {
    union { unsigned u; float f; } x; x.u = (unsigned)u << 16; return x.f;
}
__device__ __forceinline__ unsigned short f2bf(float f) {
    union { float f; unsigned u; } x; x.f = f;
    unsigned r = x.u + 0x7fffu + ((x.u >> 16) & 1u);
    return (unsigned short)(r >> 16);
}

// ---------------------------------------------------------------------------
// Weight prep: convert to bf16, fold conv into wceff, pad everything to
// [*][256] rows x 256-k pitch so ALL stages share one N=256 code path.
//   W1b    [256][256]  (k>=128 zero)            @ 0        (65536)
//   wceffb [4][256][256] (rows n>=96 zero)      @ 65536    (262144)
//   Wcatb  [4][256][256] (k>=96 zero)           @ 327680   (262144)
//   Wf1b   [4][256][256]                        @ 589824   (262144)
//   Wf2b   [4][256][256]                        @ 851968   (262144)
//   bceff  [4][256] f32 (cols>=96 zero)         @ 1114112 shorts
// Total threads: 1114112 = 4352 * 256.
// ---------------------------------------------------------------------------
__global__ __launch_bounds__(256) void prep(
    const float* __restrict__ filters,
    const float* __restrict__ Wc1, const float* __restrict__ Wc2, const float* __restrict__ Wc3,
    const float* __restrict__ bc1, const float* __restrict__ bc2, const float* __restrict__ bc3,
    const float* __restrict__ W1, const float* __restrict__ Wcat,
    const float* __restrict__ Wf1, const float* __restrict__ Wf2,
    unsigned short* __restrict__ W1b, unsigned short* __restrict__ wceffb,
    float* __restrict__ bceff, unsigned short* __restrict__ Wcatb,
    unsigned short* __restrict__ Wf1b, unsigned short* __restrict__ Wf2b)
{
    int idx = blockIdx.x * 256 + threadIdx.x;
    if (idx < 65536) {
        int n = idx >> 8, k = idx & 255;
        W1b[idx] = (k < 128) ? f2bf(W1[n * 128 + k]) : (unsigned short)0;
    } else if (idx < 327680) {               // wceffb [4][256][256]
        int j = idx - 65536;
        int i = j >> 16, n = (j >> 8) & 255, h = j & 255;
        if (n < 96) {
            int c = n >> 5, jj = n & 31;
            const float* Wc = (c == 0) ? Wc1 : (c == 1) ? Wc2 : Wc3;
            const float* f  = filters + c * 25;
            float acc = 0.f;
            #pragma unroll
            for (int k = 0; k < 25; ++k) {
                int hh = h + 12 - k;
                if (hh >= 0 && hh < 256) acc += f[k] * Wc[(i * 32 + jj) * 256 + hh];
            }
            wceffb[j] = f2bf(acc);
            if (h == 0) {
                const float* bc = (c == 0) ? bc1 : (c == 1) ? bc2 : bc3;
                bceff[i * 256 + n] = bc[i * 32 + jj];
            }
        } else {
            wceffb[j] = 0;
            if (h == 0) bceff[i * 256 + n] = 0.f;
        }
    } else if (idx < 589824) {               // Wcatb [4][256][256], k>=96 zero
        int j = idx - 327680;
        int i = j >> 16, rem = j & 65535, n = rem >> 8, k = rem & 255;
        Wcatb[j] = (k < 96) ? f2bf(Wcat[(i * 256 + n) * 96 + k]) : (unsigned short)0;
    } else if (idx < 851968) {               // Wf1b [4][256][256]
        int j = idx - 589824;
        Wf1b[j] = f2bf(Wf1[j]);
    } else if (idx < 1114112) {              // Wf2b [4][256][256]
        int j = idx - 851968;
        Wf2b[j] = f2bf(Wf2[j]);
    }
}

// ---------------------------------------------------------------------------
// Persistent mega-kernel, COMPACT CODE: one rolled stage loop (17 iters),
// one rolled K-chunk loop (runtime nkc), one shared epilogue. ~3KB hot code.
// 1024 blocks x 256 threads (4 waves = wn 0..3), 32 rows/block (mt 0..1).
// acc = mfma(A=W_frag, B=act_frag): D col(lane&15)=batch row,
// D row((lane>>4)*4+reg)=out channel. act LDS = 1KB frag tiles, slot=lane*16B.
// LDS: act 16KB + hbuf 16KB + lnred 1KB = 33KB -> 4 blocks/CU.
// ---------------------------------------------------------------------------
__global__ __launch_bounds__(256, 4) void mega(
    const float* __restrict__ x,
    const unsigned short* __restrict__ W1b, const float* __restrict__ b1,
    const float* __restrict__ a0p, const float* __restrict__ g0, const float* __restrict__ be0,
    const unsigned short* __restrict__ wceffb, const float* __restrict__ bceff,
    const unsigned short* __restrict__ Wcatb, const float* __restrict__ bcat,
    const float* __restrict__ g1, const float* __restrict__ be1,
    const unsigned short* __restrict__ Wf1b, const float* __restrict__ bf1,
    const float* __restrict__ af,
    const unsigned short* __restrict__ Wf2b, const float* __restrict__ bf2,
    const float* __restrict__ g2, const float* __restrict__ be2,
    const float* __restrict__ Wout, const float* __restrict__ boutp,
    float* __restrict__ outg)
{
    __shared__ __align__(16) unsigned short act[8192];    // 16KB [2mt][8kblk][512]
    __shared__ __align__(16) unsigned short hbuf[8192];   // 16KB
    __shared__ __align__(16) float lnred[256];            // 1KB

    const int tid  = threadIdx.x;
    const int lane = tid & 63;
    const int wn   = tid >> 6;               // 0..3
    const int l15  = lane & 15;
    const int hi   = lane >> 4;
    const int rowbase = blockIdx.x * 32;
    float* dotp = (float*)hbuf;              // overlay, used only in final stage

    // phase 0: stage x (f32) -> act fragment tiles (bf16), kblk 0..3 (verified R6)
    {
        const int r = tid >> 3, q = tid & 7;
        const float* xp = x + (size_t)(rowbase + r) * 128 + q * 16;
        #pragma unroll
        for (int gi = 0; gi < 4; ++gi) {
            const float4 xv = *(const float4*)(xp + gi * 4);
            const int j = q * 16 + gi * 4;
            const ushort4 o = {f2bf(xv.x), f2bf(xv.y), f2bf(xv.z), f2bf(xv.w)};
            *(ushort4*)(act + ((r >> 4) * 8 + (j >> 5)) * 512
                        + ((r & 15) + ((j >> 3) & 3) * 16) * 8 + (j & 7)) = o;
        }
        __syncthreads();
    }

    for (int s = 0; s < 17; ++s) {
        // ---- decode stage (all wave-uniform) ----
        const int phase = (s == 0) ? 0 : ((s - 1) & 3) + 1;
        const int it    = (s == 0) ? 0 : (s - 1) >> 2;
        const unsigned short *Wg, *in;
        const unsigned short *res = nullptr;
        unsigned short *out;
        const float *bias, *g = nullptr, *be = nullptr, *alphap = nullptr;
        int nkc, actmode, nstore = 256, fdot = 0;
        switch (phase) {
          case 0:
            Wg = W1b; bias = b1; in = act; out = act;
            nkc = 4; actmode = 1; alphap = a0p; g = g0; be = be0; break;
          case 1:
            Wg = wceffb + it * 65536; bias = bceff + it * 256; in = act; out = hbuf;
            nkc = 8; actmode = 2; nstore = 128; break;
          case 2:
            Wg = Wcatb + it * 65536; bias = bcat + it * 256; in = hbuf; out = act;
            nkc = 4; actmode = 0; res = act; g = g1 + it * 256; be = be1 + it * 256; break;
          case 3:
            Wg = Wf1b + it * 65536; bias = bf1 + it * 256; in = act; out = hbuf;
            nkc = 8; actmode = 1; alphap = af + it; break;
          default:
            Wg = Wf2b + it * 65536; bias = bf2 + it * 256; in = hbuf; out = act;
            nkc = 8; actmode = 0; res = act; g = g2 + it * 256; be = be2 + it * 256;
            fdot = (s == 16); break;
        }

        // ---- K loop: W global->VGPR 2-deep ping-pong, A from LDS ----
        f32x4 acc[2][4];
        #pragma unroll
        for (int mt = 0; mt < 2; ++mt)
            #pragma unroll
            for (int nt = 0; nt < 4; ++nt) acc[mt][nt] = (f32x4){0.f, 0.f, 0.f, 0.f};

        const unsigned short* wbase = Wg + ((size_t)(wn * 4) * 16 + l15) * 256 + hi * 8;
        const unsigned short* abase = in + lane * 8;
        bf16x8 w0[4], w1[4], a0[2], a1[2];

        #define LOADW(dst, kc) { _Pragma("unroll") \
            for (int nt = 0; nt < 4; ++nt) \
                dst[nt] = *(const bf16x8*)(wbase + nt * 16 * 256 + (kc) * 32); }
        #define LOADA(dst, kc) { _Pragma("unroll") \
            for (int mt = 0; mt < 2; ++mt) \
                dst[mt] = *(const bf16x8*)(abase + (mt * 8 + (kc)) * 512); }
        #define FMAS(areg, wreg) { \
            __builtin_amdgcn_s_setprio(1); \
            _Pragma("unroll") \
            for (int mt = 0; mt < 2; ++mt) { _Pragma("unroll") \
                for (int nt = 0; nt < 4; ++nt) \
                    acc[mt][nt] = __builtin_amdgcn_mfma_f32_16x16x32_bf16( \
                        wreg[nt], areg[mt], acc[mt][nt], 0, 0, 0); } \
            __builtin_amdgcn_s_setprio(0); }

        LOADW(w0, 0); LOADA(a0, 0);
        for (int kc = 0; kc < nkc; kc += 2) {
            LOADW(w1, kc + 1); LOADA(a1, kc + 1);
            FMAS(a0, w0);
            if (kc + 2 < nkc) { LOADW(w0, kc + 2); LOADA(a0, kc + 2); }
            FMAS(a1, w1);
        }
        #undef LOADW
        #undef LOADA
        #undef FMAS

        // ---- epilogue: bias -> act -> res -> (LN) -> store/dot ----
        const float alpha = alphap ? alphap[0] : 0.1f;
        float vv[2][4][4];
        #pragma unroll
        for (int mt = 0; mt < 2; ++mt) {
            #pragma unroll
            for (int nt = 0; nt < 4; ++nt) {
                const int nb = wn * 64 + nt * 16 + hi * 4;
                const float4 bs = *(const float4*)(bias + nb);
                float t0 = acc[mt][nt][0] + bs.x;
                float t1 = acc[mt][nt][1] + bs.y;
                float t2 = acc[mt][nt][2] + bs.z;
                float t3 = acc[mt][nt][3] + bs.w;
                if (actmode) {
                    t0 = t0 >= 0.f ? t0 : alpha * t0;
                    t1 = t1 >= 0.f ? t1 : alpha * t1;
                    t2 = t2 >= 0.f ? t2 : alpha * t2;
                    t3 = t3 >= 0.f ? t3 : alpha * t3;
                }
                if (res) {
                    const int ro = (mt * 8 + (nb >> 5)) * 512
                                 + (l15 + ((nb >> 3) & 3) * 16) * 8 + (nb & 7);
                    const ushort4 rv = *(const ushort4*)(res + ro);
                    t0 += bf2f(rv.x); t1 += bf2f(rv.y); t2 += bf2f(rv.z); t3 += bf2f(rv.w);
                }
                vv[mt][nt][0] = t0; vv[mt][nt][1] = t1;
                vv[mt][nt][2] = t2; vv[mt][nt][3] = t3;
            }
        }

        float mean[2], rstd[2];
        if (g) {
            #pragma unroll
            for (int mt = 0; mt < 2; ++mt) {
                float sm = 0.f, q = 0.f;
                #pragma unroll
                for (int nt = 0; nt < 4; ++nt)
                    #pragma unroll
                    for (int r = 0; r < 4; ++r) { const float v = vv[mt][nt][r]; sm += v; q += v * v; }
                sm += __shfl_xor(sm, 16); sm += __shfl_xor(sm, 32);
                q  += __shfl_xor(q, 16);  q  += __shfl_xor(q, 32);
                if (hi == 0)
                    *(float2*)(lnred + (mt * 16 + l15) * 8 + wn * 2) = make_float2(sm, q);
            }
            __syncthreads();   // orders all K-loop reads before in-place stores
            #pragma unroll
            for (int mt = 0; mt < 2; ++mt) {
                const int m = mt * 16 + l15;
                const float4 p0 = *(const float4*)(lnred + m * 8);
                const float4 p1 = *(const float4*)(lnred + m * 8 + 4);
                const float sm = p0.x + p0.z + p1.x + p1.z;
                const float q  = p0.y + p0.w + p1.y + p1.w;
                const float mu = sm * (1.f / 256.f);
                mean[mt] = mu;
                rstd[mt] = rsqrtf(q * (1.f / 256.f) - mu * mu + 1e-5f);
            }
        }

        #pragma unroll
        for (int mt = 0; mt < 2; ++mt) {
            float dp = 0.f;
            #pragma unroll
            for (int nt = 0; nt < 4; ++nt) {
                const int nb = wn * 64 + nt * 16 + hi * 4;
                float o0 = vv[mt][nt][0], o1 = vv[mt][nt][1];
                float o2 = vv[mt][nt][2], o3 = vv[mt][nt][3];
                if (g) {
                    const float4 gv = *(const float4*)(g + nb);
                    const float4 bv = *(const float4*)(be + nb);
                    o0 = (o0 - mean[mt]) * rstd[mt] * gv.x + bv.x;
                    o1 = (o1 - mean[mt]) * rstd[mt] * gv.y + bv.y;
                    o2 = (o2 - mean[mt]) * rstd[mt] * gv.z + bv.z;
                    o3 = (o3 - mean[mt]) * rstd[mt] * gv.w + bv.w;
                }
                if (!fdot) {
                    if (nb < nstore) {
                        const ushort4 ov = {f2bf(o0), f2bf(o1), f2bf(o2), f2bf(o3)};
                        *(ushort4*)(out + (mt * 8 + (nb >> 5)) * 512
                                    + (l15 + ((nb >> 3) & 3) * 16) * 8 + (nb & 7)) = ov;
                    }
                } else {
                    const float4 wv = *(const float4*)(Wout + nb);
                    dp += o0 * wv.x + o1 * wv.y + o2 * wv.z + o3 * wv.w;
                }
            }
            if (fdot) {
                dp += __shfl_xor(dp, 16); dp += __shfl_xor(dp, 32);
                if (hi == 0) dotp[(mt * 16 + l15) * 4 + wn] = dp;
            }
        }
        if (fdot) {
            __syncthreads();
            if (tid < 32) {
                const float4 pp = *(const float4*)(dotp + tid * 4);
                outg[rowbase + tid] = pp.x + pp.y + pp.z + pp.w + boutp[0];
            }
        }
        __syncthreads();   // stage-end: stores visible, reads done
    }
}

extern "C" void kernel_launch(void* const* d_in, const int* in_sizes, int n_in,
                              void* d_out, int out_size, void* d_ws, size_t ws_size,
                              hipStream_t stream)
{
    const float* x       = (const float*)d_in[0];
    const float* filters = (const float*)d_in[1];
    const float* W1      = (const float*)d_in[2];
    const float* b1      = (const float*)d_in[3];
    const float* a0      = (const float*)d_in[4];
    const float* g0      = (const float*)d_in[5];
    const float* be0     = (const float*)d_in[6];
    const float* Wc1     = (const float*)d_in[7];
    const float* bc1     = (const float*)d_in[8];
    const float* Wc2     = (const float*)d_in[9];
    const float* bc2     = (const float*)d_in[10];
    const float* Wc3     = (const float*)d_in[11];
    const float* bc3     = (const float*)d_in[12];
    const float* Wcat    = (const float*)d_in[13];
    const float* bcat    = (const float*)d_in[14];
    const float* g1      = (const float*)d_in[15];
    const float* be1     = (const float*)d_in[16];
    const float* Wf1     = (const float*)d_in[17];
    const float* bf1     = (const float*)d_in[18];
    const float* af      = (const float*)d_in[19];
    const float* Wf2     = (const float*)d_in[20];
    const float* bf2     = (const float*)d_in[21];
    const float* g2      = (const float*)d_in[22];
    const float* be2     = (const float*)d_in[23];
    const float* Wout    = (const float*)d_in[24];
    const float* boutp   = (const float*)d_in[25];
    float* outf = (float*)d_out;

    unsigned short* p = (unsigned short*)d_ws;
    unsigned short* W1b    = p;               // 65536
    unsigned short* wceffb = p + 65536;       // 262144
    unsigned short* Wcatb  = p + 327680;      // 262144
    unsigned short* Wf1b   = p + 589824;      // 262144
    unsigned short* Wf2b   = p + 851968;      // 262144
    float*          bceff  = (float*)(p + 1114112);  // 1024 floats

    prep<<<dim3(4352), dim3(256), 0, stream>>>(
        filters, Wc1, Wc2, Wc3, bc1, bc2, bc3, W1, Wcat, Wf1, Wf2,
        W1b, wceffb, bceff, Wcatb, Wf1b, Wf2b);

    mega<<<dim3(1024), dim3(256), 0, stream>>>(
        x, W1b, b1, a0, g0, be0, wceffb, bceff, Wcatb, bcat, g1, be1,
        Wf1b, bf1, af, Wf2b, bf2, g2, be2, Wout, boutp, outf);
}

// Round 8
// 193.636 us; speedup vs baseline: 1.3440x; 1.3440x over previous
//
#include <hip/hip_runtime.h>

typedef __attribute__((ext_vector_type(8))) short bf16x8;
typedef __attribute__((ext_vector_type(4))) float f32x4;

__device__ __forceinline__ float bf2f(unsigned short u) {
    union { unsigned u; float f; } x; x.u = (unsigned)u << 16; return x.f;
}
__device__ __forceinline__ unsigned short f2bf(float f) {
    union { float f; unsigned u; } x; x.f = f;
    unsigned r = x.u + 0x7fffu + ((x.u >> 16) & 1u);
    return (unsigned short)(r >> 16);
}

#define GLDS(src, dst) __builtin_amdgcn_global_load_lds( \
    (const __attribute__((address_space(1))) void*)(src), \
    (__attribute__((address_space(3))) void*)(dst), 16, 0, 0)

// ---------------------------------------------------------------------------
// Weight prep (verified R7): bf16 convert, conv folded into wceff, all padded
// to [256][256] per block-matrix.
//   W1b    [256][256]  (k>=128 zero)            @ 0        (65536)
//   wceffb [4][256][256] (rows n>=96 zero)      @ 65536    (262144)
//   Wcatb  [4][256][256] (k>=96 zero)           @ 327680   (262144)
//   Wf1b   [4][256][256]                        @ 589824   (262144)
//   Wf2b   [4][256][256]                        @ 851968   (262144)
//   bceff  [4][256] f32 (cols>=96 zero)         @ 1114112 shorts
// ---------------------------------------------------------------------------
__global__ __launch_bounds__(256) void prep(
    const float* __restrict__ filters,
    const float* __restrict__ Wc1, const float* __restrict__ Wc2, const float* __restrict__ Wc3,
    const float* __restrict__ bc1, const float* __restrict__ bc2, const float* __restrict__ bc3,
    const float* __restrict__ W1, const float* __restrict__ Wcat,
    const float* __restrict__ Wf1, const float* __restrict__ Wf2,
    unsigned short* __restrict__ W1b, unsigned short* __restrict__ wceffb,
    float* __restrict__ bceff, unsigned short* __restrict__ Wcatb,
    unsigned short* __restrict__ Wf1b, unsigned short* __restrict__ Wf2b)
{
    int idx = blockIdx.x * 256 + threadIdx.x;
    if (idx < 65536) {
        int n = idx >> 8, k = idx & 255;
        W1b[idx] = (k < 128) ? f2bf(W1[n * 128 + k]) : (unsigned short)0;
    } else if (idx < 327680) {
        int j = idx - 65536;
        int i = j >> 16, n = (j >> 8) & 255, h = j & 255;
        if (n < 96) {
            int c = n >> 5, jj = n & 31;
            const float* Wc = (c == 0) ? Wc1 : (c == 1) ? Wc2 : Wc3;
            const float* f  = filters + c * 25;
            float acc = 0.f;
            #pragma unroll
            for (int k = 0; k < 25; ++k) {
                int hh = h + 12 - k;
                if (hh >= 0 && hh < 256) acc += f[k] * Wc[(i * 32 + jj) * 256 + hh];
            }
            wceffb[j] = f2bf(acc);
            if (h == 0) {
                const float* bc = (c == 0) ? bc1 : (c == 1) ? bc2 : bc3;
                bceff[i * 256 + n] = bc[i * 32 + jj];
            }
        } else {
            wceffb[j] = 0;
            if (h == 0) bceff[i * 256 + n] = 0.f;
        }
    } else if (idx < 589824) {
        int j = idx - 327680;
        int i = j >> 16, rem = j & 65535, n = rem >> 8, k = rem & 255;
        Wcatb[j] = (k < 96) ? f2bf(Wcat[(i * 256 + n) * 96 + k]) : (unsigned short)0;
    } else if (idx < 851968) {
        int j = idx - 589824;
        Wf1b[j] = f2bf(Wf1[j]);
    } else if (idx < 1114112) {
        int j = idx - 851968;
        Wf2b[j] = f2bf(Wf2[j]);
    }
}

// ---------------------------------------------------------------------------
// Persistent mega-kernel: 256 blocks x 512 threads (8 waves: 2 wm x 4 wn),
// 128 rows/block, 1 block/CU. Rolled 17-stage loop.
// All LDS via direct __shared__ indexing (ds_read/ds_write guaranteed).
// W: GLDS double-buffer, issue-early -> MFMA -> vmcnt(0) -> s_barrier.
// acc = mfma(W_frag, act_frag): D col(lane&15)=row m, D row(hi*4+reg)=chan n.
// LDS: bufs 2x64KB + wstg 32KB = 160KB (lnred/dotp overlay wstg in epilogue).
// ---------------------------------------------------------------------------
__global__ __launch_bounds__(512, 1) void mega(
    const float* __restrict__ x,
    const unsigned short* __restrict__ W1b, const float* __restrict__ b1,
    const float* __restrict__ a0p, const float* __restrict__ g0, const float* __restrict__ be0,
    const unsigned short* __restrict__ wceffb, const float* __restrict__ bceff,
    const unsigned short* __restrict__ Wcatb, const float* __restrict__ bcat,
    const float* __restrict__ g1, const float* __restrict__ be1,
    const unsigned short* __restrict__ Wf1b, const float* __restrict__ bf1,
    const float* __restrict__ af,
    const unsigned short* __restrict__ Wf2b, const float* __restrict__ bf2,
    const float* __restrict__ g2, const float* __restrict__ be2,
    const float* __restrict__ Wout, const float* __restrict__ boutp,
    float* __restrict__ outg)
{
    __shared__ __align__(16) unsigned short bufs[2][32768];  // 2 x 64KB act
    __shared__ __align__(16) unsigned short wstg[16384];     // 2 x 16KB W stage

    const int tid  = threadIdx.x;
    const int lane = tid & 63;
    const int wave = tid >> 6;          // 0..7
    const int wm   = wave >> 2;         // 0..1 (64 rows each)
    const int wn   = wave & 3;          // 0..3 (64 cols each)
    const int l15  = lane & 15;
    const int hi   = lane >> 4;
    const int rowbase = blockIdx.x * 128;

    // phase 0: stage x (f32) -> bufs[0] fragment tiles (bf16), K=128
    {
        const int r = tid >> 2, q = tid & 3;
        const float* xp = x + (size_t)(rowbase + r) * 128 + q * 32;
        #pragma unroll
        for (int gi = 0; gi < 8; ++gi) {
            const float4 xv = *(const float4*)(xp + gi * 4);
            const int j = q * 32 + gi * 4;
            const ushort4 o = {f2bf(xv.x), f2bf(xv.y), f2bf(xv.z), f2bf(xv.w)};
            *(ushort4*)&bufs[0][((r >> 4) * 8 + (j >> 5)) * 512
                        + ((r & 15) + ((j >> 3) & 3) * 16) * 8 + (j & 7)] = o;
        }
        __syncthreads();
    }

    for (int s = 0; s < 17; ++s) {
        // ---- decode stage (wave-uniform) ----
        const int phase = (s == 0) ? 0 : ((s - 1) & 3) + 1;
        const int it    = (s == 0) ? 0 : (s - 1) >> 2;
        const unsigned short* Wg;
        const float *bias, *g = nullptr, *be = nullptr, *alphap = nullptr;
        int inb, outb, nkc, actmode, nstore = 256, fdot = 0, hasres = 0;
        switch (phase) {
          case 0: Wg = W1b; bias = b1; inb = 0; outb = 0;
                  nkc = 4; actmode = 1; alphap = a0p; g = g0; be = be0; break;
          case 1: Wg = wceffb + it * 65536; bias = bceff + it * 256; inb = 0; outb = 1;
                  nkc = 8; actmode = 2; nstore = 128; break;
          case 2: Wg = Wcatb + it * 65536; bias = bcat + it * 256; inb = 1; outb = 0;
                  nkc = 4; actmode = 0; hasres = 1;
                  g = g1 + it * 256; be = be1 + it * 256; break;
          case 3: Wg = Wf1b + it * 65536; bias = bf1 + it * 256; inb = 0; outb = 1;
                  nkc = 8; actmode = 1; alphap = af + it; break;
          default: Wg = Wf2b + it * 65536; bias = bf2 + it * 256; inb = 1; outb = 0;
                  nkc = 8; actmode = 0; hasres = 1;
                  g = g2 + it * 256; be = be2 + it * 256;
                  fdot = (s == 16); break;
        }

        f32x4 acc[4][4];
        #pragma unroll
        for (int mt = 0; mt < 4; ++mt)
            #pragma unroll
            for (int nt = 0; nt < 4; ++nt) acc[mt][nt] = (f32x4){0.f, 0.f, 0.f, 0.f};

        // W chunk staging: 16 tiles/chunk (1KB each); wave stages tiles 2w,2w+1.
        const int t0 = wave * 2;
        const unsigned short* wsrc0 = Wg + (size_t)(t0 * 16 + l15) * 256 + hi * 8;
        const unsigned short* wsrc1 = wsrc0 + 16 * 256;

        // prologue: chunk 0 -> buf 0
        GLDS(wsrc0, &wstg[t0 * 512]);
        GLDS(wsrc1, &wstg[t0 * 512 + 512]);
        asm volatile("s_waitcnt vmcnt(0) lgkmcnt(0)" ::: "memory");
        __builtin_amdgcn_s_barrier();

        int buf = 0;
        for (int kc = 0; kc < nkc; ++kc) {
            // issue next chunk's loads FIRST (latency hides under MFMAs)
            if (kc + 1 < nkc) {
                const int nb2 = (buf ^ 1) * 8192;
                GLDS(wsrc0 + (kc + 1) * 32, &wstg[nb2 + t0 * 512]);
                GLDS(wsrc1 + (kc + 1) * 32, &wstg[nb2 + t0 * 512 + 512]);
            }
            bf16x8 afr[4], wfr[4];
            #pragma unroll
            for (int mt = 0; mt < 4; ++mt)
                afr[mt] = *(const bf16x8*)&bufs[inb][((wm * 4 + mt) * 8 + kc) * 512 + lane * 8];
            #pragma unroll
            for (int nt = 0; nt < 4; ++nt)
                wfr[nt] = *(const bf16x8*)&wstg[buf * 8192 + (wn * 4 + nt) * 512 + lane * 8];
            #pragma unroll
            for (int mt = 0; mt < 4; ++mt)
                #pragma unroll
                for (int nt = 0; nt < 4; ++nt)
                    acc[mt][nt] = __builtin_amdgcn_mfma_f32_16x16x32_bf16(
                        wfr[nt], afr[mt], acc[mt][nt], 0, 0, 0);
            // wait own next-chunk loads landed, then sync all waves
            asm volatile("s_waitcnt vmcnt(0) lgkmcnt(0)" ::: "memory");
            __builtin_amdgcn_s_barrier();
            buf ^= 1;
        }

        // ---- epilogue: bias -> act -> res -> (LN) -> store/dot (R4-verified) ----
        float* lnred = (float*)wstg;          // 1024 f32 (W staging dead now)
        float* dotp  = (float*)wstg + 1024;   // 512 f32
        const float alpha = alphap ? alphap[0] : 0.1f;
        float vv[4][4][4];
        #pragma unroll
        for (int mt = 0; mt < 4; ++mt) {
            #pragma unroll
            for (int nt = 0; nt < 4; ++nt) {
                const int nb = wn * 64 + nt * 16 + hi * 4;
                const float4 bs = *(const float4*)(bias + nb);
                float u0 = acc[mt][nt][0] + bs.x;
                float u1 = acc[mt][nt][1] + bs.y;
                float u2 = acc[mt][nt][2] + bs.z;
                float u3 = acc[mt][nt][3] + bs.w;
                if (actmode) {
                    u0 = u0 >= 0.f ? u0 : alpha * u0;
                    u1 = u1 >= 0.f ? u1 : alpha * u1;
                    u2 = u2 >= 0.f ? u2 : alpha * u2;
                    u3 = u3 >= 0.f ? u3 : alpha * u3;
                }
                if (hasres) {
                    const int ro = ((wm * 4 + mt) * 8 + (nb >> 5)) * 512
                                 + (l15 + ((nb >> 3) & 3) * 16) * 8 + (nb & 7);
                    const ushort4 rv = *(const ushort4*)&bufs[0][ro];
                    u0 += bf2f(rv.x); u1 += bf2f(rv.y); u2 += bf2f(rv.z); u3 += bf2f(rv.w);
                }
                vv[mt][nt][0] = u0; vv[mt][nt][1] = u1;
                vv[mt][nt][2] = u2; vv[mt][nt][3] = u3;
            }
        }

        float mean[4], rstd[4];
        if (g) {
            #pragma unroll
            for (int mt = 0; mt < 4; ++mt) {
                float sm = 0.f, q = 0.f;
                #pragma unroll
                for (int nt = 0; nt < 4; ++nt)
                    #pragma unroll
                    for (int r = 0; r < 4; ++r) { const float v = vv[mt][nt][r]; sm += v; q += v * v; }
                sm += __shfl_xor(sm, 16); sm += __shfl_xor(sm, 32);
                q  += __shfl_xor(q, 16);  q  += __shfl_xor(q, 32);
                if (hi == 0)
                    *(float2*)(lnred + (wm * 64 + mt * 16 + l15) * 8 + wn * 2) = make_float2(sm, q);
            }
            __syncthreads();
            #pragma unroll
            for (int mt = 0; mt < 4; ++mt) {
                const int m = wm * 64 + mt * 16 + l15;
                const float4 p0 = *(const float4*)(lnred + m * 8);
                const float4 p1 = *(const float4*)(lnred + m * 8 + 4);
                const float sm = p0.x + p0.z + p1.x + p1.z;
                const float q  = p0.y + p0.w + p1.y + p1.w;
                const float mu = sm * (1.f / 256.f);
                mean[mt] = mu;
                rstd[mt] = rsqrtf(q * (1.f / 256.f) - mu * mu + 1e-5f);
            }
        }

        #pragma unroll
        for (int mt = 0; mt < 4; ++mt) {
            float dp = 0.f;
            #pragma unroll
            for (int nt = 0; nt < 4; ++nt) {
                const int nb = wn * 64 + nt * 16 + hi * 4;
                float o0 = vv[mt][nt][0], o1 = vv[mt][nt][1];
                float o2 = vv[mt][nt][2], o3 = vv[mt][nt][3];
                if (g) {
                    const float4 gv = *(const float4*)(g + nb);
                    const float4 bv = *(const float4*)(be + nb);
                    o0 = (o0 - mean[mt]) * rstd[mt] * gv.x + bv.x;
                    o1 = (o1 - mean[mt]) * rstd[mt] * gv.y + bv.y;
                    o2 = (o2 - mean[mt]) * rstd[mt] * gv.z + bv.z;
                    o3 = (o3 - mean[mt]) * rstd[mt] * gv.w + bv.w;
                }
                if (!fdot) {
                    if (nb < nstore) {
                        const ushort4 ov = {f2bf(o0), f2bf(o1), f2bf(o2), f2bf(o3)};
                        *(ushort4*)&bufs[outb][((wm * 4 + mt) * 8 + (nb >> 5)) * 512
                                    + (l15 + ((nb >> 3) & 3) * 16) * 8 + (nb & 7)] = ov;
                    }
                } else {
                    const float4 wv = *(const float4*)(Wout + nb);
                    dp += o0 * wv.x + o1 * wv.y + o2 * wv.z + o3 * wv.w;
                }
            }
            if (fdot) {
                dp += __shfl_xor(dp, 16); dp += __shfl_xor(dp, 32);
                if (hi == 0) dotp[(wm * 64 + mt * 16 + l15) * 4 + wn] = dp;
            }
        }
        if (fdot) {
            __syncthreads();
            if (tid < 128) {
                const float4 pp = *(const float4*)(dotp + tid * 4);
                outg[rowbase + tid] = pp.x + pp.y + pp.z + pp.w + boutp[0];
            }
        }
        __syncthreads();   // stage-end: stores visible, reads done
    }
}

extern "C" void kernel_launch(void* const* d_in, const int* in_sizes, int n_in,
                              void* d_out, int out_size, void* d_ws, size_t ws_size,
                              hipStream_t stream)
{
    const float* x       = (const float*)d_in[0];
    const float* filters = (const float*)d_in[1];
    const float* W1      = (const float*)d_in[2];
    const float* b1      = (const float*)d_in[3];
    const float* a0      = (const float*)d_in[4];
    const float* g0      = (const float*)d_in[5];
    const float* be0     = (const float*)d_in[6];
    const float* Wc1     = (const float*)d_in[7];
    const float* bc1     = (const float*)d_in[8];
    const float* Wc2     = (const float*)d_in[9];
    const float* bc2     = (const float*)d_in[10];
    const float* Wc3     = (const float*)d_in[11];
    const float* bc3     = (const float*)d_in[12];
    const float* Wcat    = (const float*)d_in[13];
    const float* bcat    = (const float*)d_in[14];
    const float* g1      = (const float*)d_in[15];
    const float* be1     = (const float*)d_in[16];
    const float* Wf1     = (const float*)d_in[17];
    const float* bf1     = (const float*)d_in[18];
    const float* af      = (const float*)d_in[19];
    const float* Wf2     = (const float*)d_in[20];
    const float* bf2     = (const float*)d_in[21];
    const float* g2      = (const float*)d_in[22];
    const float* be2     = (const float*)d_in[23];
    const float* Wout    = (const float*)d_in[24];
    const float* boutp   = (const float*)d_in[25];
    float* outf = (float*)d_out;

    unsigned short* p = (unsigned short*)d_ws;
    unsigned short* W1b    = p;               // 65536
    unsigned short* wceffb = p + 65536;       // 262144
    unsigned short* Wcatb  = p + 327680;      // 262144
    unsigned short* Wf1b   = p + 589824;      // 262144
    unsigned short* Wf2b   = p + 851968;      // 262144
    float*          bceff  = (float*)(p + 1114112);  // 1024 floats

    prep<<<dim3(4352), dim3(256), 0, stream>>>(
        filters, Wc1, Wc2, Wc3, bc1, bc2, bc3, W1, Wcat, Wf1, Wf2,
        W1b, wceffb, bceff, Wcatb, Wf1b, Wf2b);

    mega<<<dim3(256), dim3(512), 0, stream>>>(
        x, W1b, b1, a0, g0, be0, wceffb, bceff, Wcatb, bcat, g1, be1,
        Wf1b, bf1, af, Wf2b, bf2, g2, be2, Wout, boutp, outf);
}

// Round 9
// 183.382 us; speedup vs baseline: 1.4191x; 1.0559x over previous
//
#include <hip/hip_runtime.h>

typedef __attribute__((ext_vector_type(8))) short bf16x8;
typedef __attribute__((ext_vector_type(4))) float f32x4;

__device__ __forceinline__ float bf2f(unsigned short u) {
    union { unsigned u; float f; } x; x.u = (unsigned)u << 16; return x.f;
}
__device__ __forceinline__ unsigned short f2bf(float f) {
    union { float f; unsigned u; } x; x.f = f;
    unsigned r = x.u + 0x7fffu + ((x.u >> 16) & 1u);
    return (unsigned short)(r >> 16);
}

#define GLDS(src, dst) __builtin_amdgcn_global_load_lds( \
    (const __attribute__((address_space(1))) void*)(src), \
    (__attribute__((address_space(3))) void*)(dst), 16, 0, 0)

// ---------------------------------------------------------------------------
// Weight prep: 17 logical [256 n][256 k] bf16 matrices, stored FRAGMENT-TILED:
//   matrix m at wt + m*65536, layout [t 0..15][kc 0..7][lane 0..63][e 0..7]
//   where n = t*16 + (lane&15), k = kc*32 + (lane>>4)*8 + e.
// Consumer GLDS then reads base + lane*16B: fully coalesced.
// Matrices: m0=W1(k<128), m1-4=wceff[it](n<96, conv-folded), m5-8=Wcat[it](k<96),
//           m9-12=Wf1[it], m13-16=Wf2[it]. Zeros elsewhere.
// bceff [4][256] f32 (cols>=96 zero) appended at wt + 17*65536 shorts.
// ---------------------------------------------------------------------------
__global__ __launch_bounds__(256) void prep(
    const float* __restrict__ filters,
    const float* __restrict__ Wc1, const float* __restrict__ Wc2, const float* __restrict__ Wc3,
    const float* __restrict__ bc1, const float* __restrict__ bc2, const float* __restrict__ bc3,
    const float* __restrict__ W1, const float* __restrict__ Wcat,
    const float* __restrict__ Wf1, const float* __restrict__ Wf2,
    unsigned short* __restrict__ wt, float* __restrict__ bceff)
{
    int idx = blockIdx.x * 256 + threadIdx.x;
    if (idx < 1114112) {
        const int m    = idx >> 16;          // 0..16
        const int j    = idx & 65535;
        const int t    = j >> 12;
        const int kc   = (j >> 9) & 7;
        const int lane = (j >> 3) & 63;
        const int e    = j & 7;
        const int n = t * 16 + (lane & 15);
        const int k = kc * 32 + (lane >> 4) * 8 + e;
        float v = 0.f;
        if (m == 0) {
            if (k < 128) v = W1[n * 128 + k];
        } else if (m <= 4) {
            if (n < 96) {
                const int it = m - 1, c = n >> 5, jj = n & 31;
                const float* Wc = (c == 0) ? Wc1 : (c == 1) ? Wc2 : Wc3;
                const float* f  = filters + c * 25;
                float acc = 0.f;
                #pragma unroll
                for (int q = 0; q < 25; ++q) {
                    int hh = k + 12 - q;
                    if (hh >= 0 && hh < 256) acc += f[q] * Wc[(it * 32 + jj) * 256 + hh];
                }
                v = acc;
            }
        } else if (m <= 8) {
            const int it = m - 5;
            if (k < 96) v = Wcat[(it * 256 + n) * 96 + k];
        } else if (m <= 12) {
            const int it = m - 9;
            v = Wf1[(it * 256 + n) * 256 + k];
        } else {
            const int it = m - 13;
            v = Wf2[(it * 256 + n) * 256 + k];
        }
        wt[idx] = f2bf(v);
    } else if (idx < 1115136) {
        const int j = idx - 1114112;         // [4][256]
        const int it = j >> 8, n = j & 255;
        float v = 0.f;
        if (n < 96) {
            const int c = n >> 5, jj = n & 31;
            const float* bc = (c == 0) ? bc1 : (c == 1) ? bc2 : bc3;
            v = bc[it * 32 + jj];
        }
        bceff[j] = v;
    }
}

// ---------------------------------------------------------------------------
// Persistent mega-kernel (R8 structure, coalesced tiled-W GLDS):
// 256 blocks x 512 threads (8 waves: 2 wm x 4 wn), 128 rows/block, 1 block/CU.
// acc = mfma(W_frag, act_frag): D col(lane&15)=row m, D row(hi*4+reg)=chan n.
// LDS: bufs 2x64KB act + wstg 2x16KB W double-buffer = 160KB.
// ---------------------------------------------------------------------------
__global__ __launch_bounds__(512, 1) void mega(
    const float* __restrict__ x,
    const unsigned short* __restrict__ wt, const float* __restrict__ bceff,
    const float* __restrict__ b1,
    const float* __restrict__ a0p, const float* __restrict__ g0, const float* __restrict__ be0,
    const float* __restrict__ bcat, const float* __restrict__ g1, const float* __restrict__ be1,
    const float* __restrict__ bf1, const float* __restrict__ af,
    const float* __restrict__ bf2, const float* __restrict__ g2, const float* __restrict__ be2,
    const float* __restrict__ Wout, const float* __restrict__ boutp,
    float* __restrict__ outg)
{
    __shared__ __align__(16) unsigned short bufs[2][32768];  // 2 x 64KB act
    __shared__ __align__(16) unsigned short wstg[16384];     // 2 x 16KB W stage

    const int tid  = threadIdx.x;
    const int lane = tid & 63;
    const int wave = tid >> 6;          // 0..7
    const int wm   = wave >> 2;         // 0..1 (64 rows each)
    const int wn   = wave & 3;          // 0..3 (64 cols each)
    const int l15  = lane & 15;
    const int hi   = lane >> 4;
    const int rowbase = blockIdx.x * 128;

    // phase 0: stage x (f32) -> bufs[0] fragment tiles (bf16), K=128
    {
        const int r = tid >> 2, q = tid & 3;
        const float* xp = x + (size_t)(rowbase + r) * 128 + q * 32;
        #pragma unroll
        for (int gi = 0; gi < 8; ++gi) {
            const float4 xv = *(const float4*)(xp + gi * 4);
            const int j = q * 32 + gi * 4;
            const ushort4 o = {f2bf(xv.x), f2bf(xv.y), f2bf(xv.z), f2bf(xv.w)};
            *(ushort4*)&bufs[0][((r >> 4) * 8 + (j >> 5)) * 512
                        + ((r & 15) + ((j >> 3) & 3) * 16) * 8 + (j & 7)] = o;
        }
        __syncthreads();
    }

    for (int s = 0; s < 17; ++s) {
        // ---- decode stage (wave-uniform) ----
        const int phase = (s == 0) ? 0 : ((s - 1) & 3) + 1;
        const int it    = (s == 0) ? 0 : (s - 1) >> 2;
        int wmidx;
        const float *bias, *g = nullptr, *be = nullptr, *alphap = nullptr;
        int inb, outb, nkc, actmode, nstore = 256, fdot = 0, hasres = 0;
        switch (phase) {
          case 0: wmidx = 0; bias = b1; inb = 0; outb = 0;
                  nkc = 4; actmode = 1; alphap = a0p; g = g0; be = be0; break;
          case 1: wmidx = 1 + it; bias = bceff + it * 256; inb = 0; outb = 1;
                  nkc = 8; actmode = 2; nstore = 128; break;
          case 2: wmidx = 5 + it; bias = bcat + it * 256; inb = 1; outb = 0;
                  nkc = 4; actmode = 0; hasres = 1;
                  g = g1 + it * 256; be = be1 + it * 256; break;
          case 3: wmidx = 9 + it; bias = bf1 + it * 256; inb = 0; outb = 1;
                  nkc = 8; actmode = 1; alphap = af + it; break;
          default: wmidx = 13 + it; bias = bf2 + it * 256; inb = 1; outb = 0;
                  nkc = 8; actmode = 0; hasres = 1;
                  g = g2 + it * 256; be = be2 + it * 256;
                  fdot = (s == 16); break;
        }
        const unsigned short* Wg = wt + (size_t)wmidx * 65536;

        f32x4 acc[4][4];
        #pragma unroll
        for (int mt = 0; mt < 4; ++mt)
            #pragma unroll
            for (int nt = 0; nt < 4; ++nt) acc[mt][nt] = (f32x4){0.f, 0.f, 0.f, 0.f};

        // W staging: tiled source (t*8+kc)*512 + lane*8 shorts — coalesced 1KB.
        // Wave stages tiles t0=2*wave, t0+1 each chunk.
        const int t0 = wave * 2;
        const unsigned short* wsrc0 = Wg + (size_t)(t0 * 8) * 512 + lane * 8;
        const unsigned short* wsrc1 = Wg + (size_t)((t0 + 1) * 8) * 512 + lane * 8;

        // prologue: chunk 0 -> buf 0
        GLDS(wsrc0, &wstg[t0 * 512]);
        GLDS(wsrc1, &wstg[t0 * 512 + 512]);
        asm volatile("s_waitcnt vmcnt(0) lgkmcnt(0)" ::: "memory");
        __builtin_amdgcn_s_barrier();

        int buf = 0;
        for (int kc = 0; kc < nkc; ++kc) {
            if (kc + 1 < nkc) {     // issue next chunk first; hides under MFMAs
                const int nb2 = (buf ^ 1) * 8192;
                GLDS(wsrc0 + (kc + 1) * 512, &wstg[nb2 + t0 * 512]);
                GLDS(wsrc1 + (kc + 1) * 512, &wstg[nb2 + t0 * 512 + 512]);
            }
            bf16x8 afr[4], wfr[4];
            #pragma unroll
            for (int mt = 0; mt < 4; ++mt)
                afr[mt] = *(const bf16x8*)&bufs[inb][((wm * 4 + mt) * 8 + kc) * 512 + lane * 8];
            #pragma unroll
            for (int nt = 0; nt < 4; ++nt)
                wfr[nt] = *(const bf16x8*)&wstg[buf * 8192 + (wn * 4 + nt) * 512 + lane * 8];
            #pragma unroll
            for (int mt = 0; mt < 4; ++mt)
                #pragma unroll
                for (int nt = 0; nt < 4; ++nt)
                    acc[mt][nt] = __builtin_amdgcn_mfma_f32_16x16x32_bf16(
                        wfr[nt], afr[mt], acc[mt][nt], 0, 0, 0);
            asm volatile("s_waitcnt vmcnt(0) lgkmcnt(0)" ::: "memory");
            __builtin_amdgcn_s_barrier();
            buf ^= 1;
        }

        // ---- epilogue: bias -> act -> res -> (LN) -> store/dot (R8-verified) ----
        float* lnred = (float*)wstg;          // 1024 f32 (W staging dead now)
        float* dotp  = (float*)wstg + 1024;   // 512 f32
        const float alpha = alphap ? alphap[0] : 0.1f;
        float vv[4][4][4];
        #pragma unroll
        for (int mt = 0; mt < 4; ++mt) {
            #pragma unroll
            for (int nt = 0; nt < 4; ++nt) {
                const int nb = wn * 64 + nt * 16 + hi * 4;
                const float4 bs = *(const float4*)(bias + nb);
                float u0 = acc[mt][nt][0] + bs.x;
                float u1 = acc[mt][nt][1] + bs.y;
                float u2 = acc[mt][nt][2] + bs.z;
                float u3 = acc[mt][nt][3] + bs.w;
                if (actmode) {
                    u0 = u0 >= 0.f ? u0 : alpha * u0;
                    u1 = u1 >= 0.f ? u1 : alpha * u1;
                    u2 = u2 >= 0.f ? u2 : alpha * u2;
                    u3 = u3 >= 0.f ? u3 : alpha * u3;
                }
                if (hasres) {
                    const int ro = ((wm * 4 + mt) * 8 + (nb >> 5)) * 512
                                 + (l15 + ((nb >> 3) & 3) * 16) * 8 + (nb & 7);
                    const ushort4 rv = *(const ushort4*)&bufs[0][ro];
                    u0 += bf2f(rv.x); u1 += bf2f(rv.y); u2 += bf2f(rv.z); u3 += bf2f(rv.w);
                }
                vv[mt][nt][0] = u0; vv[mt][nt][1] = u1;
                vv[mt][nt][2] = u2; vv[mt][nt][3] = u3;
            }
        }

        float mean[4], rstd[4];
        if (g) {
            #pragma unroll
            for (int mt = 0; mt < 4; ++mt) {
                float sm = 0.f, q = 0.f;
                #pragma unroll
                for (int nt = 0; nt < 4; ++nt)
                    #pragma unroll
                    for (int r = 0; r < 4; ++r) { const float v = vv[mt][nt][r]; sm += v; q += v * v; }
                sm += __shfl_xor(sm, 16); sm += __shfl_xor(sm, 32);
                q  += __shfl_xor(q, 16);  q  += __shfl_xor(q, 32);
                if (hi == 0)
                    *(float2*)(lnred + (wm * 64 + mt * 16 + l15) * 8 + wn * 2) = make_float2(sm, q);
            }
            __syncthreads();
            #pragma unroll
            for (int mt = 0; mt < 4; ++mt) {
                const int m = wm * 64 + mt * 16 + l15;
                const float4 p0 = *(const float4*)(lnred + m * 8);
                const float4 p1 = *(const float4*)(lnred + m * 8 + 4);
                const float sm = p0.x + p0.z + p1.x + p1.z;
                const float q  = p0.y + p0.w + p1.y + p1.w;
                const float mu = sm * (1.f / 256.f);
                mean[mt] = mu;
                rstd[mt] = rsqrtf(q * (1.f / 256.f) - mu * mu + 1e-5f);
            }
        }

        #pragma unroll
        for (int mt = 0; mt < 4; ++mt) {
            float dp = 0.f;
            #pragma unroll
            for (int nt = 0; nt < 4; ++nt) {
                const int nb = wn * 64 + nt * 16 + hi * 4;
                float o0 = vv[mt][nt][0], o1 = vv[mt][nt][1];
                float o2 = vv[mt][nt][2], o3 = vv[mt][nt][3];
                if (g) {
                    const float4 gv = *(const float4*)(g + nb);
                    const float4 bv = *(const float4*)(be + nb);
                    o0 = (o0 - mean[mt]) * rstd[mt] * gv.x + bv.x;
                    o1 = (o1 - mean[mt]) * rstd[mt] * gv.y + bv.y;
                    o2 = (o2 - mean[mt]) * rstd[mt] * gv.z + bv.z;
                    o3 = (o3 - mean[mt]) * rstd[mt] * gv.w + bv.w;
                }
                if (!fdot) {
                    if (nb < nstore) {
                        const ushort4 ov = {f2bf(o0), f2bf(o1), f2bf(o2), f2bf(o3)};
                        *(ushort4*)&bufs[outb][((wm * 4 + mt) * 8 + (nb >> 5)) * 512
                                    + (l15 + ((nb >> 3) & 3) * 16) * 8 + (nb & 7)] = ov;
                    }
                } else {
                    const float4 wv = *(const float4*)(Wout + nb);
                    dp += o0 * wv.x + o1 * wv.y + o2 * wv.z + o3 * wv.w;
                }
            }
            if (fdot) {
                dp += __shfl_xor(dp, 16); dp += __shfl_xor(dp, 32);
                if (hi == 0) dotp[(wm * 64 + mt * 16 + l15) * 4 + wn] = dp;
            }
        }
        if (fdot) {
            __syncthreads();
            if (tid < 128) {
                const float4 pp = *(const float4*)(dotp + tid * 4);
                outg[rowbase + tid] = pp.x + pp.y + pp.z + pp.w + boutp[0];
            }
        }
        __syncthreads();   // stage-end: stores visible, reads done
    }
}

extern "C" void kernel_launch(void* const* d_in, const int* in_sizes, int n_in,
                              void* d_out, int out_size, void* d_ws, size_t ws_size,
                              hipStream_t stream)
{
    const float* x       = (const float*)d_in[0];
    const float* filters = (const float*)d_in[1];
    const float* W1      = (const float*)d_in[2];
    const float* b1      = (const float*)d_in[3];
    const float* a0      = (const float*)d_in[4];
    const float* g0      = (const float*)d_in[5];
    const float* be0     = (const float*)d_in[6];
    const float* Wc1     = (const float*)d_in[7];
    const float* bc1     = (const float*)d_in[8];
    const float* Wc2     = (const float*)d_in[9];
    const float* bc2     = (const float*)d_in[10];
    const float* Wc3     = (const float*)d_in[11];
    const float* bc3     = (const float*)d_in[12];
    const float* Wcat    = (const float*)d_in[13];
    const float* bcat    = (const float*)d_in[14];
    const float* g1      = (const float*)d_in[15];
    const float* be1     = (const float*)d_in[16];
    const float* Wf1     = (const float*)d_in[17];
    const float* bf1     = (const float*)d_in[18];
    const float* af      = (const float*)d_in[19];
    const float* Wf2     = (const float*)d_in[20];
    const float* bf2     = (const float*)d_in[21];
    const float* g2      = (const float*)d_in[22];
    const float* be2     = (const float*)d_in[23];
    const float* Wout    = (const float*)d_in[24];
    const float* boutp   = (const float*)d_in[25];
    float* outf = (float*)d_out;

    unsigned short* wt    = (unsigned short*)d_ws;          // 17*65536 shorts
    float*          bceff = (float*)(wt + 1114112);         // 1024 floats

    prep<<<dim3(4357), dim3(256), 0, stream>>>(
        filters, Wc1, Wc2, Wc3, bc1, bc2, bc3, W1, Wcat, Wf1, Wf2, wt, bceff);

    mega<<<dim3(256), dim3(512), 0, stream>>>(
        x, wt, bceff, b1, a0, g0, be0, bcat, g1, be1,
        bf1, af, bf2, g2, be2, Wout, boutp, outf);
}